// Round 5
// baseline (155.665 us; speedup 1.0000x reference)
//
#include <hip/hip_runtime.h>
#include <math.h>

// QNN: all gates are GF(2)-convolutions and the CNOT cascade is a linear bit
// permutation P  =>  the 16 initial basis states evolve into XOR-translates
// of ONE simulated state: probs_j(i) = probs_0(i ^ P^4(j)).
// Simulate a single 2^18 complex state (2 MB), then
// logits[j][o] = sum_d probs_0(d ^ T_j) * W[o][d] + b[o];
// out[b][o] = sigmoid(logits[idx_b][o]).
//
// Bit convention: wire w <-> bit p = 17-w.  P: out bit q (q<=16) =
// parity(i>>q); out bit 17 = parity(i & 0x1FFFF).
//
// Structure (4 graph nodes): memset(barrier ctrs) -> k_circuit (64 blocks,
// 6 phases, hand-rolled device-scope grid barrier) -> k_mm (512 blocks,
// 2-deep prefetch pipeline) -> k_finalize (reduce+lookup+sigmoid).

#define DIM (1 << 18)
#define NW 18
#define CH 64                       // k_mm chunk (d per LDS stage)
#define CPB 8                       // chunks per k_mm block
#define NMM 512                     // k_mm blocks = DIM/(CH*CPB)

__device__ __forceinline__ unsigned perm18(unsigned i) {
    unsigned s = i;
    s ^= s >> 1; s ^= s >> 2; s ^= s >> 4; s ^= s >> 8; s ^= s >> 16;
    unsigned out = s & 0x1FFFFu;
    out |= ((s ^ (i >> 17)) & 1u) << 17;
    return out;
}

__device__ __forceinline__ unsigned pinv18(unsigned b) {
    unsigned t = b & 0x1FFFFu;                 // s_0..s_16
    unsigned u = (t ^ (t >> 1)) & 0xFFFFu;     // i_0..i_15
    unsigned i17 = ((b >> 17) ^ t) & 1u;
    unsigned i16 = ((t >> 16) ^ i17) & 1u;
    return u | (i16 << 16) | (i17 << 17);
}

__device__ __forceinline__ void bfly(float2& a0, float2& a1, float c, float s) {
    float2 n0 = make_float2(c * a0.x + s * a1.y, c * a0.y - s * a1.x);
    float2 n1 = make_float2(c * a1.x + s * a0.y, c * a1.y - s * a0.x);
    a0 = n0; a1 = n1;
}

// device-scope grid barrier for 64 co-resident blocks; ctr zeroed by a
// memset node in the same graph, so replay-safe.
__device__ __forceinline__ void gridbar(unsigned* ctr, int k, unsigned nb) {
    __syncthreads();
    if (threadIdx.x == 0) {
        __threadfence();
        __hip_atomic_fetch_add(&ctr[k], 1u, __ATOMIC_ACQ_REL, __HIP_MEMORY_SCOPE_AGENT);
        while (__hip_atomic_load(&ctr[k], __ATOMIC_ACQUIRE, __HIP_MEMORY_SCOPE_AGENT) < nb)
            __builtin_amdgcn_s_sleep(8);
        __threadfence();
    }
    __syncthreads();
}

// ---- circuit phases (each block owns a 4096-element tile in LDS) -----------

__device__ void phaseA(float2* t, float2* gsh, float2* buf, const float* qw, int layer) {
    int tid = threadIdx.x;
    if (tid < 12) {
        float th = qw[layer * NW + (17 - tid)] * 0.5f;
        gsh[tid] = make_float2(cosf(th), sinf(th));
    }
    unsigned base = blockIdx.x * 4096u;
    for (int k = tid; k < 4096; k += 256) t[k] = buf[base + k];
    __syncthreads();
    for (int p = 0; p <= 11; ++p) {
        float2 g = gsh[p];
        int mlow = (1 << p) - 1;
        for (int k = tid; k < 2048; k += 256) {
            int i0 = ((k >> p) << (p + 1)) | (k & mlow);
            int i1 = i0 | (1 << p);
            bfly(t[i0], t[i1], g.x, g.y);
        }
        __syncthreads();
    }
    for (int k = tid; k < 4096; k += 256) buf[base + k] = t[k];
}

// pass B: 6 RX gates on bits 12..17 + perm P scatter.
// tile: 64 hi (bits 12..17) x 64 contiguous (bits 0..5); block = bits 6..11.
__device__ void phaseB(float2* t, float2* gsh, const float2* in, float2* out,
                       float* probs, const float* qw, int layer) {
    int tid = threadIdx.x;
    if (tid < 6) {                              // bit 12+q -> wire 5-q
        float th = qw[layer * NW + (5 - tid)] * 0.5f;
        gsh[tid] = make_float2(cosf(th), sinf(th));
    }
    int m = blockIdx.x;                         // bits 6..11
    for (int k = tid; k < 4096; k += 256) {
        int h = k >> 6, lo = k & 63;
        t[k] = in[((unsigned)h << 12) | (m << 6) | lo];
    }
    __syncthreads();
    for (int q = 0; q <= 5; ++q) {
        float2 g = gsh[q];
        int mq = (1 << q) - 1;
        for (int k = tid; k < 2048; k += 256) {
            int hh = k >> 6, lo = k & 63;
            int h0 = ((hh >> q) << (q + 1)) | (hh & mq);
            int h1 = h0 | (1 << q);
            bfly(t[(h0 << 6) | lo], t[(h1 << 6) | lo], g.x, g.y);
        }
        __syncthreads();
    }
    if (probs) {
        for (int k = tid; k < 4096; k += 256) {
            int h = k >> 6, lo = k & 63;
            unsigned i = ((unsigned)h << 12) | (m << 6) | lo;
            float2 a = t[k];
            probs[perm18(i)] = a.x * a.x + a.y * a.y;
        }
    } else {
        for (int k = tid; k < 4096; k += 256) {
            int h = k >> 6, lo = k & 63;
            unsigned i = ((unsigned)h << 12) | (m << 6) | lo;
            out[perm18(i)] = t[k];
        }
    }
}

// ---- single circuit kernel: init + 5 pass phases, 5 grid barriers ----------
__global__ __launch_bounds__(256, 4) void k_circuit(const float* qw, float2* buf0,
                                                    float2* buf1, float* probs,
                                                    unsigned* ctr) {
    __shared__ float2 t[4096];
    __shared__ float2 gsh[12];
    int tid = threadIdx.x;

    // phase 0: analytic layer-0 (post-P basis) + layer-1 gates on bits 0..11
    {
        if (tid < 12) {
            float th = qw[1 * NW + (17 - tid)] * 0.5f;
            gsh[tid] = make_float2(cosf(th), sinf(th));
        }
        float c[NW], s[NW];
#pragma unroll
        for (int w = 0; w < NW; ++w) {
            float th = qw[w] * 0.5f;
            c[w] = cosf(th); s[w] = sinf(th);
        }
        unsigned base = blockIdx.x * 4096u;
        for (int k = tid; k < 4096; k += 256) {
            unsigned i = pinv18(base + k);
            float m = 1.0f;
#pragma unroll
            for (int p = 0; p < 18; ++p)
                m *= ((i >> p) & 1u) ? s[17 - p] : c[17 - p];
            int k4 = __popc(i) & 3;
            float2 a;
            if      (k4 == 0) a = make_float2( m, 0.f);
            else if (k4 == 1) a = make_float2(0.f, -m);
            else if (k4 == 2) a = make_float2(-m, 0.f);
            else              a = make_float2(0.f,  m);
            t[k] = a;
        }
        __syncthreads();
        for (int p = 0; p <= 11; ++p) {
            float2 g = gsh[p];
            int mlow = (1 << p) - 1;
            for (int k = tid; k < 2048; k += 256) {
                int i0 = ((k >> p) << (p + 1)) | (k & mlow);
                int i1 = i0 | (1 << p);
                bfly(t[i0], t[i1], g.x, g.y);
            }
            __syncthreads();
        }
        for (int k = tid; k < 4096; k += 256) buf0[base + k] = t[k];
    }
    gridbar(ctr, 0, 64);
    phaseB(t, gsh, buf0, buf1, nullptr, qw, 1);
    gridbar(ctr, 1, 64);
    phaseA(t, gsh, buf1, qw, 2);
    gridbar(ctr, 2, 64);
    phaseB(t, gsh, buf1, buf0, nullptr, qw, 2);
    gridbar(ctr, 3, 64);
    phaseA(t, gsh, buf0, qw, 3);
    gridbar(ctr, 4, 64);
    phaseB(t, gsh, buf0, nullptr, probs, qw, 3);
}

// ---- logits partials: triple-buffered LDS, 2-chunk-deep prefetch -----------
// thread = (dq:2 | jg:2 | og:4); accumulates 4j x 4o over its d-quarter.
__global__ __launch_bounds__(256, 2) void k_mm(const float* __restrict__ p0,
                                               const float* __restrict__ W,
                                               float* __restrict__ partial) {
    __shared__ float Wl[3][64][68];
    __shared__ float Pl[3][16][68];
    int tid = threadIdx.x;
    int sj = tid >> 6;                     // 0..3
    unsigned Tj[4];
#pragma unroll
    for (int i = 0; i < 4; ++i) {
        unsigned v = (unsigned)(i * 4 + sj);
#pragma unroll
        for (int r = 0; r < 4; ++r) v = perm18(v);
        Tj[i] = v;
    }
    int so = tid >> 4;                     // 0..15 (W row in group)
    int sd = (tid & 15) * 4;               // float4 col
    int sm = tid & 63;
    int dq = tid >> 6, jg = (tid >> 4) & 3, og = tid & 15;
    unsigned d00 = (unsigned)blockIdx.x * (CH * CPB);

    float4 wreg[2][4];
    float  preg[2][4];
    float acc[4][4] = {};

    auto loadw = [&](float4* wr, unsigned d0) {
#pragma unroll
        for (int i = 0; i < 4; ++i)
            wr[i] = *(const float4*)&W[(size_t)(i * 16 + so) * DIM + d0 + sd];
    };
    auto loadp = [&](float* pr, unsigned d0) {
#pragma unroll
        for (int i = 0; i < 4; ++i)
            pr[i] = p0[(d0 ^ (Tj[i] & ~63u)) + sm];
    };
    auto commit = [&](int b, const float4* wr, const float* pr) {
#pragma unroll
        for (int i = 0; i < 4; ++i)
            *(float4*)&Wl[b][i * 16 + so][sd] = wr[i];
#pragma unroll
        for (int i = 0; i < 4; ++i)
            Pl[b][i * 4 + sj][sm ^ (Tj[i] & 63u)] = pr[i];
    };
    auto compute = [&](int b) {
#pragma unroll
        for (int it = 0; it < CH / 16; ++it) {         // 4
            int d = it * 16 + dq * 4;
            float4 pv[4], wv[4];
#pragma unroll
            for (int u = 0; u < 4; ++u) pv[u] = *(const float4*)&Pl[b][jg * 4 + u][d];
#pragma unroll
            for (int v = 0; v < 4; ++v) wv[v] = *(const float4*)&Wl[b][og + 16 * v][d];
#pragma unroll
            for (int u = 0; u < 4; ++u)
#pragma unroll
                for (int v = 0; v < 4; ++v)
                    acc[u][v] += pv[u].x * wv[v].x + pv[u].y * wv[v].y
                               + pv[u].z * wv[v].z + pv[u].w * wv[v].w;
        }
    };

    // prologue: ch0 -> buf0 (stall OK, once); ch1 -> set0; ch2 -> set1.
    loadw(wreg[0], d00);            loadp(preg[0], d00);
    commit(0, wreg[0], preg[0]);
    loadw(wreg[0], d00 + CH);       loadp(preg[0], d00 + CH);
    loadw(wreg[1], d00 + 2 * CH);   loadp(preg[1], d00 + 2 * CH);
    __syncthreads();

#pragma unroll
    for (int cc = 0; cc < CPB; ++cc) {
        compute(cc % 3);
        if (cc + 1 < CPB) {
            int set = cc & 1;
            commit((cc + 1) % 3, wreg[set], preg[set]);
            if (cc + 3 < CPB) {
                unsigned d0 = d00 + (unsigned)(cc + 3) * CH;
                loadw(wreg[set], d0);
                loadp(preg[set], d0);
            }
        }
        __syncthreads();
    }

    // reduce the 4 dq groups (reuse Wl[0] as 16KB scratch)
    float* red = &Wl[0][0][0];
#pragma unroll
    for (int u = 0; u < 4; ++u)
#pragma unroll
        for (int v = 0; v < 4; ++v)
            red[(u * 4 + v) * 256 + tid] = acc[u][v];
    __syncthreads();
    if (tid < 64) {
        int jg2 = tid >> 4, og2 = tid & 15;
#pragma unroll
        for (int u = 0; u < 4; ++u)
#pragma unroll
            for (int v = 0; v < 4; ++v) {
                int idx = u * 4 + v;
                float ssum = red[idx * 256 + tid] + red[idx * 256 + 64 + tid]
                           + red[idx * 256 + 128 + tid] + red[idx * 256 + 192 + tid];
                partial[(size_t)blockIdx.x * 1024 + (jg2 * 4 + u) * 64 + og2 + 16 * v] = ssum;
            }
    }
}

// ---- finalize: reduce partials -> logits; per-batch lookup + sigmoid -------
// 64 blocks; block b owns idx = b>>2, o in [(b&3)*16, +16). No cross-block dep.
__global__ __launch_bounds__(256) void k_finalize(const float* __restrict__ partial,
                                                  const float* __restrict__ bias,
                                                  const int* __restrict__ x,
                                                  float* __restrict__ out) {
    int b = blockIdx.x;
    int tid = threadIdx.x;
    int ji = tid & 15, ci = tid >> 4;
    int jo = b * 16 + ji;
    float sum = 0.f;
#pragma unroll 8
    for (int c = ci; c < NMM; c += 16)
        sum += partial[(size_t)c * 1024 + jo];
    __shared__ float red[16][17];
    __shared__ float lg[16];
    __shared__ int sidx[32];
    red[ci][ji] = sum;
    if (tid < 32) {
        const int* xb = x + (size_t)tid * (16384 * 4);
        sidx[tid] = 8 * xb[0] + 4 * xb[1] + 2 * xb[2] + xb[3];
    }
    __syncthreads();
    if (ci == 0) {
        float s = 0.f;
#pragma unroll
        for (int k = 0; k < 16; ++k) s += red[k][ji];
        lg[ji] = s + bias[jo & 63];
    }
    __syncthreads();
    int myidx = b >> 2, o0 = (b & 3) * 16;
#pragma unroll
    for (int r = 0; r < 2; ++r) {
        int slot = tid + 256 * r;          // 512 slots = 32 batches x 16 o's
        int bb = slot >> 4, k = slot & 15;
        if (sidx[bb] == myidx) {
            float z = lg[k];
            out[bb * 64 + o0 + k] = 1.f / (1.f + expf(-z));
        }
    }
}

extern "C" void kernel_launch(void* const* d_in, const int* in_sizes, int n_in,
                              void* d_out, int out_size, void* d_ws, size_t ws_size,
                              hipStream_t stream) {
    const int*   x    = (const int*)d_in[0];
    const float* qw   = (const float*)d_in[1];
    const float* W    = (const float*)d_in[2];
    const float* bias = (const float*)d_in[3];
    float* out = (float*)d_out;

    char* ws = (char*)d_ws;
    unsigned* ctr     = (unsigned*)ws;                     // 5 barrier counters
    float2*   buf0    = (float2*)(ws + (1ull << 20));      // 2 MB
    float2*   buf1    = (float2*)(ws + (4ull << 20));      // 2 MB
    float*    probs   = (float*)(ws + (8ull << 20));       // 1 MB
    float*    partial = (float*)(ws + (12ull << 20));      // 2 MB

    hipMemsetAsync(ctr, 0, 256, stream);
    k_circuit<<<64, 256, 0, stream>>>(qw, buf0, buf1, probs, ctr);
    k_mm<<<NMM, 256, 0, stream>>>(probs, W, partial);
    k_finalize<<<64, 256, 0, stream>>>(partial, bias, x, out);
}